// Round 12
// baseline (1619.602 us; speedup 1.0000x reference)
//
#include <hip/hip_runtime.h>
#include <hip/hip_bf16.h>
#include <math.h>

#define N_ORIG 200000
#define NS_    500000
#define ES_    1000000
#define B_     256
#define P_     32
#define D_     128
#define BP_    8192
#define RW_    20
#define PRW_   8
#define TH_    64
#define CH_    512

static inline int cdiv_l(long a, long b){ return (int)((a + b - 1) / b); }

typedef unsigned short ushort_t;
typedef __attribute__((ext_vector_type(8))) short gmx_bv8;   // 8 bf16 (4 VGPRs)
typedef __attribute__((ext_vector_type(4))) float gmx_fv4;   // 4 f32 acc

__device__ __forceinline__ float b2f(ushort_t u){
    union { unsigned int i; float f; } c; c.i = ((unsigned int)u) << 16; return c.f;
}
__device__ __forceinline__ ushort_t f2b(float f){
    union { float f; unsigned int u; } c; c.f = f;
    unsigned int u = c.u;
    u += 0x7fffu + ((u >> 16) & 1u);      // RNE
    return (ushort_t)(u >> 16);
}
__device__ __forceinline__ float4 b2f4(ushort4 v){
    return make_float4(b2f(v.x), b2f(v.y), b2f(v.z), b2f(v.w));
}
__device__ __forceinline__ ushort4 f2b4(float4 v){
    ushort4 r; r.x = f2b(v.x); r.y = f2b(v.y); r.z = f2b(v.z); r.w = f2b(v.w); return r;
}

__device__ __forceinline__ float gelu_t(float x){
    float t = tanhf(0.7978845608028654f * (x + 0.044715f * x * x * x));
    return 0.5f * x * (1.0f + t);
}

// ---------------- diagnostics ----------------
__global__ void k_breadcrumb(float* __restrict__ out, int n, float v){
    int i = blockIdx.x * 256 + threadIdx.x;
    if (i < n) out[i] = v;
}

// ---------------- degree histograms ----------------
__global__ void k_deg_edges(const int* __restrict__ dstv, const int* __restrict__ perm,
                            int* __restrict__ deg, int* __restrict__ dst2){
    int e = blockIdx.x * 256 + threadIdx.x;
    if (e >= ES_) return;
    int nd = perm[dstv[e]];
    dst2[e] = nd;
    atomicAdd(&deg[nd], 1);
}

__global__ void k_deg_ns(const int* __restrict__ bx, const int* __restrict__ nm,
                         int* __restrict__ pdeg, int* __restrict__ ndeg){
    int i = blockIdx.x * 256 + threadIdx.x;
    if (i >= NS_) return;
    atomicAdd(&pdeg[bx[i]], 1);
    atomicAdd(&ndeg[nm[i]], 1);
}

// ---------------- generic 3-phase exclusive scan ----------------
__global__ __launch_bounds__(256)
void k_scan1(int* __restrict__ a, int* __restrict__ bsum, int n){
    __shared__ int sb[256];
    int tid = threadIdx.x;
    long base = (long)blockIdx.x * 1024 + tid * 4;
    int v0 = 0, v1 = 0, v2 = 0, v3 = 0;
    if (base + 0 < n) v0 = a[base + 0];
    if (base + 1 < n) v1 = a[base + 1];
    if (base + 2 < n) v2 = a[base + 2];
    if (base + 3 < n) v3 = a[base + 3];
    int tsum = v0 + v1 + v2 + v3;
    sb[tid] = tsum;
    __syncthreads();
    for (int o = 1; o < 256; o <<= 1){
        int t = (tid >= o) ? sb[tid - o] : 0;
        __syncthreads();
        sb[tid] += t;
        __syncthreads();
    }
    int excl = sb[tid] - tsum;
    if (tid == 255) bsum[blockIdx.x] = sb[255];
    if (base + 0 < n) a[base + 0] = excl;
    if (base + 1 < n) a[base + 1] = excl + v0;
    if (base + 2 < n) a[base + 2] = excl + v0 + v1;
    if (base + 3 < n) a[base + 3] = excl + v0 + v1 + v2;
}

__global__ __launch_bounds__(512)
void k_scan2(int* __restrict__ bsum, int nb){
    __shared__ int sb[512];
    int tid = threadIdx.x;
    int orig = (tid < nb) ? bsum[tid] : 0;
    sb[tid] = orig;
    __syncthreads();
    for (int o = 1; o < 512; o <<= 1){
        int t = (tid >= o) ? sb[tid - o] : 0;
        __syncthreads();
        sb[tid] += t;
        __syncthreads();
    }
    if (tid < nb) bsum[tid] = sb[tid] - orig;
}

__global__ void k_scan3(int* __restrict__ a, const int* __restrict__ bsum,
                        int* __restrict__ cursor, int n, int total){
    long i = (long)blockIdx.x * 256 + threadIdx.x;
    if (i < n){
        int v = a[i] + bsum[i >> 10];
        a[i] = v;
        cursor[i] = v;
    } else if (i == n){
        a[n] = total;
    }
}

// ---------------- CSR scatters ----------------
__global__ void k_scatter_ns(const int* __restrict__ bx, const int* __restrict__ nm,
                             int* __restrict__ cur_p, int* __restrict__ cur_n,
                             int* __restrict__ perm, int* __restrict__ bx2,
                             int* __restrict__ nm2, int* __restrict__ plist){
    int i = blockIdx.x * 256 + threadIdx.x;
    if (i >= NS_) return;
    int b = bx[i], n = nm[i];
    int pn = atomicAdd(&cur_n[n], 1);      // node-major slot
    perm[i] = pn;
    bx2[pn] = b;
    nm2[pn] = n;
    int pp = atomicAdd(&cur_p[b], 1);      // patch-major slot
    plist[pp] = pn;
}

__global__ void k_scatter_edges(const int* __restrict__ srcv, const int* __restrict__ dst2,
                                const int* __restrict__ ea, const int* __restrict__ em,
                                const int* __restrict__ nm,
                                int* __restrict__ cursor, int* __restrict__ epack){
    int e = blockIdx.x * 256 + threadIdx.x;
    if (e >= ES_) return;
    int pos = atomicAdd(&cursor[dst2[e]], 1);
    epack[pos] = nm[srcv[e]] | (ea[em[e]] << 18);
}

// ---------------- node encoder (compact) ----------------
__global__ void k_encode(const int* __restrict__ xa, const float* __restrict__ rw,
                         const float* __restrict__ aemb, const float* __restrict__ rwW,
                         const float* __restrict__ rwb, ushort_t* __restrict__ xn){
    long i = (long)blockIdx.x * 256 + threadIdx.x;
    if (i >= (long)N_ORIG * 32) return;
    int n = (int)(i >> 5), q = (int)(i & 31);
    const float4* aemb4 = (const float4*)aemb;
    const float4* rwW4  = (const float4*)rwW;
    const float4* rwb4  = (const float4*)rwb;
    float4 v = aemb4[(long)xa[n] * 32 + q];
    float4 bb = rwb4[q];
    v.x += bb.x; v.y += bb.y; v.z += bb.z; v.w += bb.w;
    const float* rr = rw + (long)n * RW_;
    #pragma unroll
    for (int k = 0; k < RW_; k++){
        float rv = rr[k];
        float4 ww = rwW4[k * 32 + q];
        v.x = fmaf(rv, ww.x, v.x); v.y = fmaf(rv, ww.y, v.y);
        v.z = fmaf(rv, ww.z, v.z); v.w = fmaf(rv, ww.w, v.w);
    }
    ((ushort4*)xn)[i] = f2b4(v);
}

// ---------------- fused patch-pool + U-GEMM ----------------
__global__ __launch_bounds__(256)
void k_pool_gemm(const ushort_t* __restrict__ xs, const int* __restrict__ prp,
                 const int* __restrict__ plist, const float* __restrict__ W,
                 const float* __restrict__ bvec, ushort_t* __restrict__ out){
    __shared__ char sInB[16 * 256];     // 4 KB bf16 pooled tile (XOR-swizzled rows)
    __shared__ int sPrp[17];
    int tid = threadIdx.x;
    int wid = tid >> 6, lane = tid & 63;
    int colA = lane & 15, rgrp = lane >> 4;
    int c0 = 32 * wid + colA, c1 = c0 + 16;
    float bias0 = bvec[c0], bias1 = bvec[c1];
    union { gmx_bv8 v; short s[8]; } bf0[4], bf1[4];
    #pragma unroll
    for (int kb = 0; kb < 4; kb++){
        int kr = kb * 32 + 8 * rgrp;
        #pragma unroll
        for (int j = 0; j < 8; j++){
            bf0[kb].s[j] = (short)f2b(W[(kr + j) * D_ + c0]);
            bf1[kb].s[j] = (short)f2b(W[(kr + j) * D_ + c1]);
        }
    }
    int p0 = blockIdx.x * 16;
    if (tid < 17) sPrp[tid] = prp[p0 + tid];
    __syncthreads();
    const ushort4* xs4 = (const ushort4*)xs;
    #pragma unroll
    for (int it = 0; it < 2; it++){
        int k = tid + it * 256;
        int r = k >> 5, q = k & 31;
        int j0 = sPrp[r], j1 = sPrp[r + 1];
        float4 s0 = make_float4(0.f,0.f,0.f,0.f), s1 = make_float4(0.f,0.f,0.f,0.f);
        float4 s2 = make_float4(0.f,0.f,0.f,0.f), s3 = make_float4(0.f,0.f,0.f,0.f);
        int j = j0;
        for (; j + 4 <= j1; j += 4){
            float4 a = b2f4(xs4[(long)plist[j] * 32 + q]);
            float4 b = b2f4(xs4[(long)plist[j + 1] * 32 + q]);
            float4 c = b2f4(xs4[(long)plist[j + 2] * 32 + q]);
            float4 d = b2f4(xs4[(long)plist[j + 3] * 32 + q]);
            s0.x += a.x; s0.y += a.y; s0.z += a.z; s0.w += a.w;
            s1.x += b.x; s1.y += b.y; s1.z += b.z; s1.w += b.w;
            s2.x += c.x; s2.y += c.y; s2.z += c.z; s2.w += c.w;
            s3.x += d.x; s3.y += d.y; s3.z += d.z; s3.w += d.w;
        }
        for (; j < j1; j++){
            float4 a = b2f4(xs4[(long)plist[j] * 32 + q]);
            s0.x += a.x; s0.y += a.y; s0.z += a.z; s0.w += a.w;
        }
        float inv = 1.f / fmaxf((float)(j1 - j0), 1.f);
        float4 v = make_float4((s0.x + s1.x + s2.x + s3.x) * inv,
                               (s0.y + s1.y + s2.y + s3.y) * inv,
                               (s0.z + s1.z + s2.z + s3.z) * inv,
                               (s0.w + s1.w + s2.w + s3.w) * inv);
        int off = (r * 256 + q * 8) ^ ((r & 7) << 4);
        *(ushort4*)&sInB[off] = f2b4(v);
    }
    __syncthreads();
    gmx_fv4 acc0 = {0.f,0.f,0.f,0.f}, acc1 = {0.f,0.f,0.f,0.f};
    #pragma unroll
    for (int kb = 0; kb < 4; kb++){
        int kslot = kb * 4 + rgrp;
        gmx_bv8 a = *(const gmx_bv8*)&sInB[(colA * 256 + kslot * 16) ^ ((colA & 7) << 4)];
        acc0 = __builtin_amdgcn_mfma_f32_16x16x32_bf16(a, bf0[kb].v, acc0, 0, 0, 0);
        acc1 = __builtin_amdgcn_mfma_f32_16x16x32_bf16(a, bf1[kb].v, acc1, 0, 0, 0);
    }
    #pragma unroll
    for (int ri = 0; ri < 4; ri++){
        long base = (long)(p0 + rgrp * 4 + ri) * D_;
        out[base + c0] = f2b(fmaxf(acc0[ri] + bias0, 0.f));
        out[base + c1] = f2b(fmaxf(acc1[ri] + bias1, 0.f));
    }
}

// ---------------- final patch pooling + PE ----------------
__global__ __launch_bounds__(128)
void k_patch_pool_sx(const ushort_t* __restrict__ xs, const int* __restrict__ prp,
                     const int* __restrict__ plist, const float* __restrict__ ppe,
                     const float* __restrict__ pW, const float* __restrict__ pb,
                     float* __restrict__ m){
    int p = blockIdx.x, d = threadIdx.x;
    int j0 = prp[p], j1 = prp[p + 1];
    float s0 = 0.f, s1 = 0.f, s2 = 0.f, s3 = 0.f;
    int j = j0;
    for (; j + 4 <= j1; j += 4){
        s0 += b2f(xs[(long)plist[j] * D_ + d]);
        s1 += b2f(xs[(long)plist[j + 1] * D_ + d]);
        s2 += b2f(xs[(long)plist[j + 2] * D_ + d]);
        s3 += b2f(xs[(long)plist[j + 3] * D_ + d]);
    }
    for (; j < j1; j++) s0 += b2f(xs[(long)plist[j] * D_ + d]);
    float s = (s0 + s1 + s2 + s3) / fmaxf((float)(j1 - j0), 1.f) + pb[d];
    #pragma unroll
    for (int k = 0; k < PRW_; k++) s = fmaf(ppe[p * PRW_ + k], pW[k * D_ + d], s);
    m[(long)p * D_ + d] = s;
}

// ---------------- pre-step reduce (sequential, nt loads on xs stream) ----------------
__global__ __launch_bounds__(128)
void k_node_resync(const ushort_t* __restrict__ xs, const ushort_t* __restrict__ subT,
                   const int* __restrict__ bx2, const int* __restrict__ nrp,
                   ushort_t* __restrict__ xn){
    int n = blockIdx.x, d = threadIdx.x;
    int j0 = nrp[n], j1 = nrp[n + 1];
    float s = 0.f;
    int j = j0;
    for (; j + 2 <= j1; j += 2){
        float va = b2f(__builtin_nontemporal_load(&xs[(long)j * D_ + d]));
        float vb = b2f(__builtin_nontemporal_load(&xs[(long)(j + 1) * D_ + d]));
        float ua = b2f(subT[(long)bx2[j] * D_ + d]);
        float ub = b2f(subT[(long)bx2[j + 1] * D_ + d]);
        s += va + ua + vb + ub;
    }
    if (j < j1){
        s += b2f(__builtin_nontemporal_load(&xs[(long)j * D_ + d]))
           + b2f(subT[(long)bx2[j] * D_ + d]);
    }
    xn[(long)n * D_ + d] = f2b(s / fmaxf((float)(j1 - j0), 1.f));
}

// ---------------- MFMA conv: 512 threads, one row-walk per thread; NT xout stores ----------------
#define CROWS 16

__global__ __launch_bounds__(512)
void k_conv_mfma(const ushort_t* __restrict__ xn, const int* __restrict__ nm2,
                 ushort_t* __restrict__ xout,
                 const int* __restrict__ rp, const int* __restrict__ epack,
                 const float* __restrict__ bond, const float* __restrict__ W,
                 const float* __restrict__ bvec){
    __shared__ char sInB[CROWS * 256];      // 4 KB bf16 A-tile (XOR-swizzled rows)
    __shared__ ushort_t sSelf[CROWS * D_];  // 4 KB raw self rows (residual)
    __shared__ int sRp[CROWS + 1];
    __shared__ int sEp[256];
    int tid = threadIdx.x;
    int wid = tid >> 6, lane = tid & 63;     // 8 waves
    int colA = lane & 15, rgrp = lane >> 4;
    int c0 = 16 * wid + colA;                // each wave owns one 16-col tile
    float bias0 = bvec[c0];
    union { gmx_bv8 v; short s[8]; } bf0[4];
    #pragma unroll
    for (int kb = 0; kb < 4; kb++){
        int kr = kb * 32 + 8 * rgrp;
        #pragma unroll
        for (int j = 0; j < 8; j++){
            bf0[kb].s[j] = (short)f2b(W[(kr + j) * D_ + c0]);
        }
    }
    const ushort4* xn4 = (const ushort4*)xn;
    const float4* bond4 = (const float4*)bond;
    const int ntiles = NS_ / CROWS;
    int r = tid >> 5, q = tid & 31;          // one (row, quarter) per thread
    for (int tile = blockIdx.x; tile < ntiles; tile += gridDim.x){
        int r0 = tile * CROWS;
        if (tid < CROWS + 1) sRp[tid] = rp[r0 + tid];
        __syncthreads();
        int eb0 = sRp[0];
        int ne = sRp[CROWS] - eb0;
        int nc = ne < 256 ? ne : 256;
        for (int k2 = tid; k2 < nc; k2 += 512) sEp[k2] = epack[eb0 + k2];
        __syncthreads();
        // ---- phase B: all 16 row-walks concurrent ----
        {
            ushort4 selfb = xn4[(long)nm2[r0 + r] * 32 + q];
            *(ushort4*)&sSelf[r * D_ + q * 4] = selfb;
            float4 v = b2f4(selfb);
            int e0 = sRp[r], e1 = sRp[r + 1];
            int e = e0;
            for (; e + 2 <= e1; e += 2){
                int i0 = e - eb0;
                int pk0 = (i0 < 256) ? sEp[i0] : epack[e];
                int pk1 = (i0 + 1 < 256) ? sEp[i0 + 1] : epack[e + 1];
                float4 u0 = b2f4(xn4[(long)(pk0 & 0x3FFFF) * 32 + q]);
                float4 u1 = b2f4(xn4[(long)(pk1 & 0x3FFFF) * 32 + q]);
                float4 b0 = bond4[((pk0 >> 18) & 7) * 32 + q];
                float4 b1 = bond4[((pk1 >> 18) & 7) * 32 + q];
                v.x += fmaxf(u0.x + b0.x, 0.f) + fmaxf(u1.x + b1.x, 0.f);
                v.y += fmaxf(u0.y + b0.y, 0.f) + fmaxf(u1.y + b1.y, 0.f);
                v.z += fmaxf(u0.z + b0.z, 0.f) + fmaxf(u1.z + b1.z, 0.f);
                v.w += fmaxf(u0.w + b0.w, 0.f) + fmaxf(u1.w + b1.w, 0.f);
            }
            if (e < e1){
                int i0 = e - eb0;
                int pk0 = (i0 < 256) ? sEp[i0] : epack[e];
                float4 u0 = b2f4(xn4[(long)(pk0 & 0x3FFFF) * 32 + q]);
                float4 b0 = bond4[((pk0 >> 18) & 7) * 32 + q];
                v.x += fmaxf(u0.x + b0.x, 0.f);
                v.y += fmaxf(u0.y + b0.y, 0.f);
                v.z += fmaxf(u0.z + b0.z, 0.f);
                v.w += fmaxf(u0.w + b0.w, 0.f);
            }
            int off = (r * 256 + q * 8) ^ ((r & 7) << 4);
            *(ushort4*)&sInB[off] = f2b4(v);
        }
        __syncthreads();
        // ---- phase C: MFMA, each wave one 16x16 D tile ----
        gmx_fv4 acc = {0.f,0.f,0.f,0.f};
        #pragma unroll
        for (int kb = 0; kb < 4; kb++){
            int kslot = kb * 4 + rgrp;
            gmx_bv8 a = *(const gmx_bv8*)&sInB[(colA * 256 + kslot * 16) ^ ((colA & 7) << 4)];
            acc = __builtin_amdgcn_mfma_f32_16x16x32_bf16(a, bf0[kb].v, acc, 0, 0, 0);
        }
        #pragma unroll
        for (int ri = 0; ri < 4; ri++){
            int prow = rgrp * 4 + ri;
            long base = (long)(r0 + prow) * D_;
            float o0 = b2f(sSelf[prow * D_ + c0]) + fmaxf(acc[ri] + bias0, 0.f);
            __builtin_nontemporal_store(f2b(o0), &xout[base + c0]);
        }
        __syncthreads();
    }
}

// ---------------- mixer: token mixing (one block per graph) ----------------
__global__ __launch_bounds__(256)
void k_token_mix(float* __restrict__ m, const float* __restrict__ g, const float* __restrict__ be,
                 const float* __restrict__ tW1, const float* __restrict__ tb1,
                 const float* __restrict__ tW2, const float* __restrict__ tb2){
    __shared__ float sy[P_][D_];        // 16 KB
    __shared__ float sh[D_][TH_ + 1];   // 33.3 KB
    int b = blockIdx.x, tid = threadIdx.x;
    float* mb = m + (long)b * P_ * D_;
    int wv = tid >> 6, ln_ = tid & 63;
    for (int r = wv; r < P_; r += 4){
        float v0 = mb[r * D_ + ln_], v1 = mb[r * D_ + 64 + ln_];
        float s = v0 + v1, ss = v0 * v0 + v1 * v1;
        #pragma unroll
        for (int o = 32; o > 0; o >>= 1){ s += __shfl_down(s, o, 64); ss += __shfl_down(ss, o, 64); }
        s = __shfl(s, 0, 64); ss = __shfl(ss, 0, 64);
        float mu = s * (1.f / 128.f);
        float var = ss * (1.f / 128.f) - mu * mu;
        float rs = rsqrtf(var + 1e-5f);
        sy[r][ln_]      = (v0 - mu) * rs * g[ln_]      + be[ln_];
        sy[r][64 + ln_] = (v1 - mu) * rs * g[64 + ln_] + be[64 + ln_];
    }
    __syncthreads();
    for (int o = tid; o < D_ * TH_; o += 256){
        int t = o & 63, d = o >> 6;
        float a = tb1[t];
        #pragma unroll
        for (int p = 0; p < P_; p++) a = fmaf(sy[p][d], tW1[p * TH_ + t], a);
        sh[d][t] = gelu_t(a);
    }
    __syncthreads();
    for (int o = tid; o < P_ * D_; o += 256){
        int d = o & 127, p = o >> 7;
        float a = tb2[p];
        #pragma unroll
        for (int t = 0; t < TH_; t++) a = fmaf(sh[d][t], tW2[t * P_ + p], a);
        mb[p * D_ + d] += a;
    }
}

// ---------------- mixer: channel mixing (16 rows per block) ----------------
__global__ __launch_bounds__(256)
void k_channel_mix(float* __restrict__ m, const float* __restrict__ g, const float* __restrict__ be,
                   const float* __restrict__ cW1, const float* __restrict__ cb1,
                   const float* __restrict__ cW2, const float* __restrict__ cb2){
    __shared__ float sy[16][D_];        // 8 KB
    __shared__ float sh[16][CH_ + 1];   // 32.8 KB
    int r0 = blockIdx.x * 16, tid = threadIdx.x;
    int wv = tid >> 6, ln_ = tid & 63;
    for (int r = wv; r < 16; r += 4){
        float v0 = m[(long)(r0 + r) * D_ + ln_], v1 = m[(long)(r0 + r) * D_ + 64 + ln_];
        float s = v0 + v1, ss = v0 * v0 + v1 * v1;
        #pragma unroll
        for (int o = 32; o > 0; o >>= 1){ s += __shfl_down(s, o, 64); ss += __shfl_down(ss, o, 64); }
        s = __shfl(s, 0, 64); ss = __shfl(ss, 0, 64);
        float mu = s * (1.f / 128.f);
        float var = ss * (1.f / 128.f) - mu * mu;
        float rs = rsqrtf(var + 1e-5f);
        sy[r][ln_]      = (v0 - mu) * rs * g[ln_]      + be[ln_];
        sy[r][64 + ln_] = (v1 - mu) * rs * g[64 + ln_] + be[64 + ln_];
    }
    __syncthreads();
    #pragma unroll
    for (int th = 0; th < 2; th++){
        int t = tid + th * 256;
        float acc[16];
        #pragma unroll
        for (int r = 0; r < 16; r++) acc[r] = cb1[t];
        for (int k = 0; k < D_; k++){
            float w = cW1[k * CH_ + t];
            #pragma unroll
            for (int r = 0; r < 16; r++) acc[r] = fmaf(sy[r][k], w, acc[r]);
        }
        #pragma unroll
        for (int r = 0; r < 16; r++) sh[r][t] = gelu_t(acc[r]);
    }
    __syncthreads();
    {
        int d = tid & 127, rbase = tid >> 7;
        float acc[8];
        #pragma unroll
        for (int q = 0; q < 8; q++) acc[q] = 0.f;
        for (int t = 0; t < CH_; t++){
            float w = cW2[t * D_ + d];
            #pragma unroll
            for (int q = 0; q < 8; q++) acc[q] = fmaf(sh[rbase + 2 * q][t], w, acc[q]);
        }
        float cb = cb2[d];
        #pragma unroll
        for (int q = 0; q < 8; q++){
            int row = r0 + rbase + 2 * q;
            m[(long)row * D_ + d] += acc[q] + cb;
        }
    }
}

// ---------------- final pooled head ----------------
__global__ __launch_bounds__(128)
void k_final(const float* __restrict__ m, const float* __restrict__ oW1, const float* __restrict__ ob1,
             const float* __restrict__ oW2, const float* __restrict__ ob2, float* __restrict__ out){
    __shared__ float sp[D_];
    __shared__ float red[128];
    int b = blockIdx.x, tid = threadIdx.x;
    float a = 0.f;
    for (int p = 0; p < P_; p++) a += m[(long)b * P_ * D_ + p * D_ + tid];
    sp[tid] = a * (1.0f / P_);
    __syncthreads();
    float h = ob1[tid];
    for (int d = 0; d < D_; d++) h = fmaf(sp[d], oW1[d * D_ + tid], h);
    h = fmaxf(h, 0.f) * oW2[tid];
    red[tid] = h;
    __syncthreads();
    for (int s = 64; s > 0; s >>= 1){
        if (tid < s) red[tid] += red[tid + s];
        __syncthreads();
    }
    if (tid == 0) out[b] = red[0] + ob2[0];
}

extern "C" void kernel_launch(void* const* d_in, const int* in_sizes, int n_in,
                              void* d_out, int out_size, void* d_ws, size_t ws_size,
                              hipStream_t stream){
    const int*   x_atom       = (const int*)  d_in[0];
    const float* rw_pe        = (const float*)d_in[1];
    const int*   edge_attr    = (const int*)  d_in[2];
    const int*   nodes_mapper = (const int*)  d_in[3];
    const int*   edges_mapper = (const int*)  d_in[4];
    const int*   edge_index   = (const int*)  d_in[5];
    const int*   batch_x      = (const int*)  d_in[6];
    const float* patch_pe     = (const float*)d_in[7];
    // d_in[8] = mask, all-true by construction -> mean pooling
    const float* atom_emb = (const float*)d_in[9];
    const float* bond_emb = (const float*)d_in[10];
    const float* rw_W  = (const float*)d_in[11];
    const float* rw_b  = (const float*)d_in[12];
    const float* prw_W = (const float*)d_in[13];
    const float* prw_b = (const float*)d_in[14];
    const float* gnn_W = (const float*)d_in[15];
    const float* gnn_b = (const float*)d_in[16];
    const float* U_W   = (const float*)d_in[17];
    const float* U_b   = (const float*)d_in[18];
    const float* ln1_g = (const float*)d_in[19];
    const float* ln1_b = (const float*)d_in[20];
    const float* tW1   = (const float*)d_in[21];
    const float* tb1   = (const float*)d_in[22];
    const float* tW2   = (const float*)d_in[23];
    const float* tb2   = (const float*)d_in[24];
    const float* ln2_g = (const float*)d_in[25];
    const float* ln2_b = (const float*)d_in[26];
    const float* cW1   = (const float*)d_in[27];
    const float* cb1   = (const float*)d_in[28];
    const float* cW2   = (const float*)d_in[29];
    const float* cb2   = (const float*)d_in[30];
    const float* oW1   = (const float*)d_in[31];
    const float* ob1   = (const float*)d_in[32];
    const float* oW2   = (const float*)d_in[33];
    const float* ob2   = (const float*)d_in[34];

    const int* srcv = edge_index;
    const int* dstv = edge_index + ES_;

    // ---- workspace layout: ~202 MB <= 256 MiB ----
    char* w = (char*)d_ws;
    size_t offXS  = 0;                                        // per-copy state [NS,128] bf16 (NODE-major)
    size_t offXN  = offXS  + (size_t)NS_ * D_ * 2;            // compact [N,128] bf16
    size_t offRP  = offXN  + (size_t)N_ORIG * D_ * 2;
    size_t offEP  = offRP  + 2000064;
    size_t offDST2= offEP  + (size_t)ES_ * 4;
    size_t offPRP = offDST2+ (size_t)ES_ * 4;
    size_t offNRP = offPRP + 32832;
    size_t offPL  = offNRP + 800064;
    size_t offPERM= offPL  + (size_t)NS_ * 4;
    size_t offBX2 = offPERM+ (size_t)NS_ * 4;
    size_t offNM2 = offBX2 + (size_t)NS_ * 4;
    size_t offBS  = offNM2 + (size_t)NS_ * 4;
    size_t offST  = offBS  + 2048;
    size_t offM   = offST  + (size_t)BP_ * D_ * 2;
    size_t needed = offM   + (size_t)BP_ * D_ * 4;

    if (ws_size < needed){
        k_breadcrumb<<<cdiv_l(out_size, 256), 256, 0, stream>>>((float*)d_out, out_size,
                                                                (float)(ws_size >> 20));
        return;
    }

    // canary: absmax ~6.7 -> pipeline died mid-way; ~0.32 -> module never ran
    k_breadcrumb<<<cdiv_l(out_size, 256), 256, 0, stream>>>((float*)d_out, out_size, 7.0f);

    ushort_t* xs = (ushort_t*)(w + offXS);
    ushort_t* xn = (ushort_t*)(w + offXN);
    int* rp    = (int*)(w + offRP);
    int* ep    = (int*)(w + offEP);
    int* dst2  = (int*)(w + offDST2);
    int* prp   = (int*)(w + offPRP);
    int* nrp   = (int*)(w + offNRP);
    int* plist = (int*)(w + offPL);
    int* perm  = (int*)(w + offPERM);
    int* bx2   = (int*)(w + offBX2);
    int* nm2   = (int*)(w + offNM2);
    int* bsum  = (int*)(w + offBS);
    ushort_t* subT = (ushort_t*)(w + offST);
    float*    mbuf = (float*)(w + offM);
    // cursors borrow xs (dead until conv 0 writes it)
    int* cur_e = (int*)(w + offXS);
    int* cur_p = (int*)(w + offXS + 4194304);
    int* cur_n = (int*)(w + offXS + 8388608);

    const int TPB = 256;

    // ---- patch & node degree histograms, scans ----
    hipMemsetAsync(prp, 0, 32832, stream);
    hipMemsetAsync(nrp, 0, 800064, stream);
    k_deg_ns<<<cdiv_l(NS_, TPB), TPB, 0, stream>>>(batch_x, nodes_mapper, prp, nrp);
    k_scan1<<<cdiv_l(BP_, 1024), TPB, 0, stream>>>(prp, bsum, BP_);
    k_scan2<<<1, 512, 0, stream>>>(bsum, cdiv_l(BP_, 1024));
    k_scan3<<<cdiv_l(BP_ + 1, TPB), TPB, 0, stream>>>(prp, bsum, cur_p, BP_, NS_);
    k_scan1<<<cdiv_l(N_ORIG, 1024), TPB, 0, stream>>>(nrp, bsum, N_ORIG);
    k_scan2<<<1, 512, 0, stream>>>(bsum, cdiv_l(N_ORIG, 1024));
    k_scan3<<<cdiv_l(N_ORIG + 1, TPB), TPB, 0, stream>>>(nrp, bsum, cur_n, N_ORIG, NS_);
    // ---- relabeling scatter (node-major) ----
    k_scatter_ns<<<cdiv_l(NS_, TPB), TPB, 0, stream>>>(batch_x, nodes_mapper, cur_p, cur_n,
                                                       perm, bx2, nm2, plist);
    // ---- edge CSR over node-major dst ----
    hipMemsetAsync(rp, 0, 2000064, stream);
    k_deg_edges<<<cdiv_l(ES_, TPB), TPB, 0, stream>>>(dstv, perm, rp, dst2);
    k_scan1<<<cdiv_l(NS_, 1024), TPB, 0, stream>>>(rp, bsum, NS_);
    k_scan2<<<1, 512, 0, stream>>>(bsum, cdiv_l(NS_, 1024));
    k_scan3<<<cdiv_l(NS_ + 1, TPB), TPB, 0, stream>>>(rp, bsum, cur_e, NS_, ES_);
    k_scatter_edges<<<cdiv_l(ES_, TPB), TPB, 0, stream>>>(srcv, dst2, edge_attr, edges_mapper,
                                                          nodes_mapper, cur_e, ep);

    // ---- encode (compact, N rows) ----
    k_encode<<<cdiv_l((long)N_ORIG * 32, TPB), TPB, 0, stream>>>(x_atom, rw_pe, atom_emb,
                                                                 rw_W, rw_b, xn);

    for (int i = 0; i < 4; i++){
        if (i > 0){
            k_pool_gemm<<<BP_ / 16, TPB, 0, stream>>>(xs, prp, plist,
                                                      U_W + (i - 1) * D_ * D_,
                                                      U_b + (i - 1) * D_, subT);
            k_node_resync<<<N_ORIG, 128, 0, stream>>>(xs, subT, bx2, nrp, xn);
        }
        k_conv_mfma<<<4096, 512, 0, stream>>>(xn, nm2, xs, rp, ep, bond_emb,
                                              gnn_W + i * D_ * D_, gnn_b + i * D_);
    }

    // ---- patch pooling + mixer ----
    k_patch_pool_sx<<<BP_, 128, 0, stream>>>(xs, prp, plist, patch_pe, prw_W, prw_b, mbuf);

    for (int l = 0; l < 2; l++){
        k_token_mix<<<B_, TPB, 0, stream>>>(mbuf, ln1_g + l * D_, ln1_b + l * D_,
                                            tW1 + l * P_ * TH_, tb1 + l * TH_,
                                            tW2 + l * TH_ * P_, tb2 + l * P_);
        k_channel_mix<<<BP_ / 16, TPB, 0, stream>>>(mbuf, ln2_g + l * D_, ln2_b + l * D_,
                                                    cW1 + l * D_ * CH_, cb1 + l * CH_,
                                                    cW2 + l * CH_ * D_, cb2 + l * D_);
    }
    k_final<<<B_, 128, 0, stream>>>(mbuf, oW1, ob1, oW2, ob2, (float*)d_out);
}

// Round 13
// 1540.604 us; speedup vs baseline: 1.0513x; 1.0513x over previous
//
#include <hip/hip_runtime.h>
#include <hip/hip_bf16.h>
#include <math.h>

#define N_ORIG 200000
#define NS_    500000
#define ES_    1000000
#define B_     256
#define P_     32
#define D_     128
#define BP_    8192
#define RW_    20
#define PRW_   8
#define TH_    64
#define CH_    512

static inline int cdiv_l(long a, long b){ return (int)((a + b - 1) / b); }

typedef unsigned short ushort_t;
typedef __attribute__((ext_vector_type(8))) short gmx_bv8;   // 8 bf16 (4 VGPRs)
typedef __attribute__((ext_vector_type(4))) float gmx_fv4;   // 4 f32 acc

__device__ __forceinline__ float b2f(ushort_t u){
    union { unsigned int i; float f; } c; c.i = ((unsigned int)u) << 16; return c.f;
}
__device__ __forceinline__ ushort_t f2b(float f){
    union { float f; unsigned int u; } c; c.f = f;
    unsigned int u = c.u;
    u += 0x7fffu + ((u >> 16) & 1u);      // RNE
    return (ushort_t)(u >> 16);
}
__device__ __forceinline__ float4 b2f4(ushort4 v){
    return make_float4(b2f(v.x), b2f(v.y), b2f(v.z), b2f(v.w));
}
__device__ __forceinline__ ushort4 f2b4(float4 v){
    ushort4 r; r.x = f2b(v.x); r.y = f2b(v.y); r.z = f2b(v.z); r.w = f2b(v.w); return r;
}

__device__ __forceinline__ float gelu_t(float x){
    float t = tanhf(0.7978845608028654f * (x + 0.044715f * x * x * x));
    return 0.5f * x * (1.0f + t);
}

// ---------------- diagnostics ----------------
__global__ void k_breadcrumb(float* __restrict__ out, int n, float v){
    int i = blockIdx.x * 256 + threadIdx.x;
    if (i < n) out[i] = v;
}

// ---------------- degree histograms ----------------
__global__ void k_deg_edges(const int* __restrict__ dstv, const int* __restrict__ perm,
                            int* __restrict__ deg, int* __restrict__ dst2){
    int e = blockIdx.x * 256 + threadIdx.x;
    if (e >= ES_) return;
    int nd = perm[dstv[e]];
    dst2[e] = nd;
    atomicAdd(&deg[nd], 1);
}

__global__ void k_deg_ns(const int* __restrict__ bx, const int* __restrict__ nm,
                         int* __restrict__ pdeg, int* __restrict__ ndeg){
    int i = blockIdx.x * 256 + threadIdx.x;
    if (i >= NS_) return;
    atomicAdd(&pdeg[bx[i]], 1);
    atomicAdd(&ndeg[nm[i]], 1);
}

// ---------------- generic 3-phase exclusive scan ----------------
__global__ __launch_bounds__(256)
void k_scan1(int* __restrict__ a, int* __restrict__ bsum, int n){
    __shared__ int sb[256];
    int tid = threadIdx.x;
    long base = (long)blockIdx.x * 1024 + tid * 4;
    int v0 = 0, v1 = 0, v2 = 0, v3 = 0;
    if (base + 0 < n) v0 = a[base + 0];
    if (base + 1 < n) v1 = a[base + 1];
    if (base + 2 < n) v2 = a[base + 2];
    if (base + 3 < n) v3 = a[base + 3];
    int tsum = v0 + v1 + v2 + v3;
    sb[tid] = tsum;
    __syncthreads();
    for (int o = 1; o < 256; o <<= 1){
        int t = (tid >= o) ? sb[tid - o] : 0;
        __syncthreads();
        sb[tid] += t;
        __syncthreads();
    }
    int excl = sb[tid] - tsum;
    if (tid == 255) bsum[blockIdx.x] = sb[255];
    if (base + 0 < n) a[base + 0] = excl;
    if (base + 1 < n) a[base + 1] = excl + v0;
    if (base + 2 < n) a[base + 2] = excl + v0 + v1;
    if (base + 3 < n) a[base + 3] = excl + v0 + v1 + v2;
}

__global__ __launch_bounds__(512)
void k_scan2(int* __restrict__ bsum, int nb){
    __shared__ int sb[512];
    int tid = threadIdx.x;
    int orig = (tid < nb) ? bsum[tid] : 0;
    sb[tid] = orig;
    __syncthreads();
    for (int o = 1; o < 512; o <<= 1){
        int t = (tid >= o) ? sb[tid - o] : 0;
        __syncthreads();
        sb[tid] += t;
        __syncthreads();
    }
    if (tid < nb) bsum[tid] = sb[tid] - orig;
}

__global__ void k_scan3(int* __restrict__ a, const int* __restrict__ bsum,
                        int* __restrict__ cursor, int n, int total){
    long i = (long)blockIdx.x * 256 + threadIdx.x;
    if (i < n){
        int v = a[i] + bsum[i >> 10];
        a[i] = v;
        cursor[i] = v;
    } else if (i == n){
        a[n] = total;
    }
}

// ---------------- CSR scatters ----------------
__global__ void k_scatter_ns(const int* __restrict__ bx, const int* __restrict__ nm,
                             int* __restrict__ cur_p, int* __restrict__ cur_n,
                             int* __restrict__ perm, int* __restrict__ bx2,
                             int* __restrict__ nm2, int* __restrict__ plist){
    int i = blockIdx.x * 256 + threadIdx.x;
    if (i >= NS_) return;
    int b = bx[i], n = nm[i];
    int pn = atomicAdd(&cur_n[n], 1);      // node-major slot
    perm[i] = pn;
    bx2[pn] = b;
    nm2[pn] = n;
    int pp = atomicAdd(&cur_p[b], 1);      // patch-major slot
    plist[pp] = pn;
}

__global__ void k_scatter_edges(const int* __restrict__ srcv, const int* __restrict__ dst2,
                                const int* __restrict__ ea, const int* __restrict__ em,
                                const int* __restrict__ nm,
                                int* __restrict__ cursor, int* __restrict__ epack){
    int e = blockIdx.x * 256 + threadIdx.x;
    if (e >= ES_) return;
    int pos = atomicAdd(&cursor[dst2[e]], 1);
    epack[pos] = nm[srcv[e]] | (ea[em[e]] << 18);
}

// ---------------- node encoder (compact) ----------------
__global__ void k_encode(const int* __restrict__ xa, const float* __restrict__ rw,
                         const float* __restrict__ aemb, const float* __restrict__ rwW,
                         const float* __restrict__ rwb, ushort_t* __restrict__ xn){
    long i = (long)blockIdx.x * 256 + threadIdx.x;
    if (i >= (long)N_ORIG * 32) return;
    int n = (int)(i >> 5), q = (int)(i & 31);
    const float4* aemb4 = (const float4*)aemb;
    const float4* rwW4  = (const float4*)rwW;
    const float4* rwb4  = (const float4*)rwb;
    float4 v = aemb4[(long)xa[n] * 32 + q];
    float4 bb = rwb4[q];
    v.x += bb.x; v.y += bb.y; v.z += bb.z; v.w += bb.w;
    const float* rr = rw + (long)n * RW_;
    #pragma unroll
    for (int k = 0; k < RW_; k++){
        float rv = rr[k];
        float4 ww = rwW4[k * 32 + q];
        v.x = fmaf(rv, ww.x, v.x); v.y = fmaf(rv, ww.y, v.y);
        v.z = fmaf(rv, ww.z, v.z); v.w = fmaf(rv, ww.w, v.w);
    }
    ((ushort4*)xn)[i] = f2b4(v);
}

// ---------------- fused patch-pool + U-GEMM (512 threads: 1 (row,quarter)/thread) ----------------
__global__ __launch_bounds__(512)
void k_pool_gemm(const ushort_t* __restrict__ xs, const int* __restrict__ prp,
                 const int* __restrict__ plist, const float* __restrict__ W,
                 const float* __restrict__ bvec, ushort_t* __restrict__ out){
    __shared__ char sInB[16 * 256];     // 4 KB bf16 pooled tile (XOR-swizzled rows)
    __shared__ int sPrp[17];
    int tid = threadIdx.x;
    int wid = tid >> 6, lane = tid & 63;     // 8 waves
    int colA = lane & 15, rgrp = lane >> 4;
    int c0 = 16 * wid + colA;                // each wave owns one 16-col tile
    float bias0 = bvec[c0];
    union { gmx_bv8 v; short s[8]; } bf0[4];
    #pragma unroll
    for (int kb = 0; kb < 4; kb++){
        int kr = kb * 32 + 8 * rgrp;
        #pragma unroll
        for (int j = 0; j < 8; j++){
            bf0[kb].s[j] = (short)f2b(W[(kr + j) * D_ + c0]);
        }
    }
    int p0 = blockIdx.x * 16;
    if (tid < 17) sPrp[tid] = prp[p0 + tid];
    __syncthreads();
    const ushort4* xs4 = (const ushort4*)xs;
    {
        int r = tid >> 5, q = tid & 31;      // one (row, quarter) per thread
        int j0 = sPrp[r], j1 = sPrp[r + 1];
        float4 s0 = make_float4(0.f,0.f,0.f,0.f), s1 = make_float4(0.f,0.f,0.f,0.f);
        float4 s2 = make_float4(0.f,0.f,0.f,0.f), s3 = make_float4(0.f,0.f,0.f,0.f);
        int j = j0;
        for (; j + 4 <= j1; j += 4){
            float4 a = b2f4(xs4[(long)plist[j] * 32 + q]);
            float4 b = b2f4(xs4[(long)plist[j + 1] * 32 + q]);
            float4 c = b2f4(xs4[(long)plist[j + 2] * 32 + q]);
            float4 d = b2f4(xs4[(long)plist[j + 3] * 32 + q]);
            s0.x += a.x; s0.y += a.y; s0.z += a.z; s0.w += a.w;
            s1.x += b.x; s1.y += b.y; s1.z += b.z; s1.w += b.w;
            s2.x += c.x; s2.y += c.y; s2.z += c.z; s2.w += c.w;
            s3.x += d.x; s3.y += d.y; s3.z += d.z; s3.w += d.w;
        }
        for (; j < j1; j++){
            float4 a = b2f4(xs4[(long)plist[j] * 32 + q]);
            s0.x += a.x; s0.y += a.y; s0.z += a.z; s0.w += a.w;
        }
        float inv = 1.f / fmaxf((float)(j1 - j0), 1.f);
        float4 v = make_float4((s0.x + s1.x + s2.x + s3.x) * inv,
                               (s0.y + s1.y + s2.y + s3.y) * inv,
                               (s0.z + s1.z + s2.z + s3.z) * inv,
                               (s0.w + s1.w + s2.w + s3.w) * inv);
        int off = (r * 256 + q * 8) ^ ((r & 7) << 4);
        *(ushort4*)&sInB[off] = f2b4(v);
    }
    __syncthreads();
    gmx_fv4 acc = {0.f,0.f,0.f,0.f};
    #pragma unroll
    for (int kb = 0; kb < 4; kb++){
        int kslot = kb * 4 + rgrp;
        gmx_bv8 a = *(const gmx_bv8*)&sInB[(colA * 256 + kslot * 16) ^ ((colA & 7) << 4)];
        acc = __builtin_amdgcn_mfma_f32_16x16x32_bf16(a, bf0[kb].v, acc, 0, 0, 0);
    }
    #pragma unroll
    for (int ri = 0; ri < 4; ri++){
        long base = (long)(p0 + rgrp * 4 + ri) * D_;
        out[base + c0] = f2b(fmaxf(acc[ri] + bias0, 0.f));
    }
}

// ---------------- final patch pooling + PE (256 threads: split j-range) ----------------
__global__ __launch_bounds__(256)
void k_patch_pool_sx(const ushort_t* __restrict__ xs, const int* __restrict__ prp,
                     const int* __restrict__ plist, const float* __restrict__ ppe,
                     const float* __restrict__ pW, const float* __restrict__ pb,
                     float* __restrict__ m){
    __shared__ float sred[128];
    int p = blockIdx.x, tid = threadIdx.x;
    int d = tid & 127, h = tid >> 7;
    int j0 = prp[p], j1 = prp[p + 1];
    int mid = (j0 + j1) >> 1;
    int a0 = h ? mid : j0, a1 = h ? j1 : mid;
    float s0 = 0.f, s1 = 0.f, s2 = 0.f, s3 = 0.f;
    int j = a0;
    for (; j + 4 <= a1; j += 4){
        s0 += b2f(xs[(long)plist[j] * D_ + d]);
        s1 += b2f(xs[(long)plist[j + 1] * D_ + d]);
        s2 += b2f(xs[(long)plist[j + 2] * D_ + d]);
        s3 += b2f(xs[(long)plist[j + 3] * D_ + d]);
    }
    for (; j < a1; j++) s0 += b2f(xs[(long)plist[j] * D_ + d]);
    float s = s0 + s1 + s2 + s3;
    if (h) sred[d] = s;
    __syncthreads();
    if (!h){
        s = (s + sred[d]) / fmaxf((float)(j1 - j0), 1.f) + pb[d];
        #pragma unroll
        for (int k = 0; k < PRW_; k++) s = fmaf(ppe[p * PRW_ + k], pW[k * D_ + d], s);
        m[(long)p * D_ + d] = s;
    }
}

// ---------------- pre-step reduce (SEQUENTIAL, node-major xs) ----------------
__global__ __launch_bounds__(128)
void k_node_resync(const ushort_t* __restrict__ xs, const ushort_t* __restrict__ subT,
                   const int* __restrict__ bx2, const int* __restrict__ nrp,
                   ushort_t* __restrict__ xn){
    int n = blockIdx.x, d = threadIdx.x;
    int j0 = nrp[n], j1 = nrp[n + 1];
    float s = 0.f;
    int j = j0;
    for (; j + 2 <= j1; j += 2){
        float va = b2f(xs[(long)j * D_ + d]);
        float vb = b2f(xs[(long)(j + 1) * D_ + d]);
        float ua = b2f(subT[(long)bx2[j] * D_ + d]);
        float ub = b2f(subT[(long)bx2[j + 1] * D_ + d]);
        s += va + ua + vb + ub;
    }
    if (j < j1){
        s += b2f(xs[(long)j * D_ + d]) + b2f(subT[(long)bx2[j] * D_ + d]);
    }
    xn[(long)n * D_ + d] = f2b(s / fmaxf((float)(j1 - j0), 1.f));
}

// ---------------- MFMA conv: 512 threads, one row-walk per thread ----------------
#define CROWS 16

__global__ __launch_bounds__(512)
void k_conv_mfma(const ushort_t* __restrict__ xn, const int* __restrict__ nm2,
                 ushort_t* __restrict__ xout,
                 const int* __restrict__ rp, const int* __restrict__ epack,
                 const float* __restrict__ bond, const float* __restrict__ W,
                 const float* __restrict__ bvec){
    __shared__ char sInB[CROWS * 256];      // 4 KB bf16 A-tile (XOR-swizzled rows)
    __shared__ ushort_t sSelf[CROWS * D_];  // 4 KB raw self rows (residual)
    __shared__ int sRp[CROWS + 1];
    __shared__ int sEp[256];
    int tid = threadIdx.x;
    int wid = tid >> 6, lane = tid & 63;     // 8 waves
    int colA = lane & 15, rgrp = lane >> 4;
    int c0 = 16 * wid + colA;                // each wave owns one 16-col tile
    float bias0 = bvec[c0];
    union { gmx_bv8 v; short s[8]; } bf0[4];
    #pragma unroll
    for (int kb = 0; kb < 4; kb++){
        int kr = kb * 32 + 8 * rgrp;
        #pragma unroll
        for (int j = 0; j < 8; j++){
            bf0[kb].s[j] = (short)f2b(W[(kr + j) * D_ + c0]);
        }
    }
    const ushort4* xn4 = (const ushort4*)xn;
    const float4* bond4 = (const float4*)bond;
    const int ntiles = NS_ / CROWS;
    int r = tid >> 5, q = tid & 31;          // one (row, quarter) per thread
    for (int tile = blockIdx.x; tile < ntiles; tile += gridDim.x){
        int r0 = tile * CROWS;
        if (tid < CROWS + 1) sRp[tid] = rp[r0 + tid];
        __syncthreads();
        int eb0 = sRp[0];
        int ne = sRp[CROWS] - eb0;
        int nc = ne < 256 ? ne : 256;
        for (int k2 = tid; k2 < nc; k2 += 512) sEp[k2] = epack[eb0 + k2];
        __syncthreads();
        // ---- phase B: all 16 row-walks concurrent ----
        {
            ushort4 selfb = xn4[(long)nm2[r0 + r] * 32 + q];
            *(ushort4*)&sSelf[r * D_ + q * 4] = selfb;
            float4 v = b2f4(selfb);
            int e0 = sRp[r], e1 = sRp[r + 1];
            int e = e0;
            for (; e + 2 <= e1; e += 2){
                int i0 = e - eb0;
                int pk0 = (i0 < 256) ? sEp[i0] : epack[e];
                int pk1 = (i0 + 1 < 256) ? sEp[i0 + 1] : epack[e + 1];
                float4 u0 = b2f4(xn4[(long)(pk0 & 0x3FFFF) * 32 + q]);
                float4 u1 = b2f4(xn4[(long)(pk1 & 0x3FFFF) * 32 + q]);
                float4 b0 = bond4[((pk0 >> 18) & 7) * 32 + q];
                float4 b1 = bond4[((pk1 >> 18) & 7) * 32 + q];
                v.x += fmaxf(u0.x + b0.x, 0.f) + fmaxf(u1.x + b1.x, 0.f);
                v.y += fmaxf(u0.y + b0.y, 0.f) + fmaxf(u1.y + b1.y, 0.f);
                v.z += fmaxf(u0.z + b0.z, 0.f) + fmaxf(u1.z + b1.z, 0.f);
                v.w += fmaxf(u0.w + b0.w, 0.f) + fmaxf(u1.w + b1.w, 0.f);
            }
            if (e < e1){
                int i0 = e - eb0;
                int pk0 = (i0 < 256) ? sEp[i0] : epack[e];
                float4 u0 = b2f4(xn4[(long)(pk0 & 0x3FFFF) * 32 + q]);
                float4 b0 = bond4[((pk0 >> 18) & 7) * 32 + q];
                v.x += fmaxf(u0.x + b0.x, 0.f);
                v.y += fmaxf(u0.y + b0.y, 0.f);
                v.z += fmaxf(u0.z + b0.z, 0.f);
                v.w += fmaxf(u0.w + b0.w, 0.f);
            }
            int off = (r * 256 + q * 8) ^ ((r & 7) << 4);
            *(ushort4*)&sInB[off] = f2b4(v);
        }
        __syncthreads();
        // ---- phase C: MFMA, each wave one 16x16 D tile ----
        gmx_fv4 acc = {0.f,0.f,0.f,0.f};
        #pragma unroll
        for (int kb = 0; kb < 4; kb++){
            int kslot = kb * 4 + rgrp;
            gmx_bv8 a = *(const gmx_bv8*)&sInB[(colA * 256 + kslot * 16) ^ ((colA & 7) << 4)];
            acc = __builtin_amdgcn_mfma_f32_16x16x32_bf16(a, bf0[kb].v, acc, 0, 0, 0);
        }
        #pragma unroll
        for (int ri = 0; ri < 4; ri++){
            int prow = rgrp * 4 + ri;
            long base = (long)(r0 + prow) * D_;
            float o0 = b2f(sSelf[prow * D_ + c0]) + fmaxf(acc[ri] + bias0, 0.f);
            xout[base + c0] = f2b(o0);
        }
        __syncthreads();
    }
}

// ---------------- mixer: token mixing (one block per graph) ----------------
__global__ __launch_bounds__(256)
void k_token_mix(float* __restrict__ m, const float* __restrict__ g, const float* __restrict__ be,
                 const float* __restrict__ tW1, const float* __restrict__ tb1,
                 const float* __restrict__ tW2, const float* __restrict__ tb2){
    __shared__ float sy[P_][D_];        // 16 KB
    __shared__ float sh[D_][TH_ + 1];   // 33.3 KB
    int b = blockIdx.x, tid = threadIdx.x;
    float* mb = m + (long)b * P_ * D_;
    int wv = tid >> 6, ln_ = tid & 63;
    for (int r = wv; r < P_; r += 4){
        float v0 = mb[r * D_ + ln_], v1 = mb[r * D_ + 64 + ln_];
        float s = v0 + v1, ss = v0 * v0 + v1 * v1;
        #pragma unroll
        for (int o = 32; o > 0; o >>= 1){ s += __shfl_down(s, o, 64); ss += __shfl_down(ss, o, 64); }
        s = __shfl(s, 0, 64); ss = __shfl(ss, 0, 64);
        float mu = s * (1.f / 128.f);
        float var = ss * (1.f / 128.f) - mu * mu;
        float rs = rsqrtf(var + 1e-5f);
        sy[r][ln_]      = (v0 - mu) * rs * g[ln_]      + be[ln_];
        sy[r][64 + ln_] = (v1 - mu) * rs * g[64 + ln_] + be[64 + ln_];
    }
    __syncthreads();
    for (int o = tid; o < D_ * TH_; o += 256){
        int t = o & 63, d = o >> 6;
        float a = tb1[t];
        #pragma unroll
        for (int p = 0; p < P_; p++) a = fmaf(sy[p][d], tW1[p * TH_ + t], a);
        sh[d][t] = gelu_t(a);
    }
    __syncthreads();
    for (int o = tid; o < P_ * D_; o += 256){
        int d = o & 127, p = o >> 7;
        float a = tb2[p];
        #pragma unroll
        for (int t = 0; t < TH_; t++) a = fmaf(sh[d][t], tW2[t * P_ + p], a);
        mb[p * D_ + d] += a;
    }
}

// ---------------- mixer: channel mixing (16 rows per block) ----------------
__global__ __launch_bounds__(256)
void k_channel_mix(float* __restrict__ m, const float* __restrict__ g, const float* __restrict__ be,
                   const float* __restrict__ cW1, const float* __restrict__ cb1,
                   const float* __restrict__ cW2, const float* __restrict__ cb2){
    __shared__ float sy[16][D_];        // 8 KB
    __shared__ float sh[16][CH_ + 1];   // 32.8 KB
    int r0 = blockIdx.x * 16, tid = threadIdx.x;
    int wv = tid >> 6, ln_ = tid & 63;
    for (int r = wv; r < 16; r += 4){
        float v0 = m[(long)(r0 + r) * D_ + ln_], v1 = m[(long)(r0 + r) * D_ + 64 + ln_];
        float s = v0 + v1, ss = v0 * v0 + v1 * v1;
        #pragma unroll
        for (int o = 32; o > 0; o >>= 1){ s += __shfl_down(s, o, 64); ss += __shfl_down(ss, o, 64); }
        s = __shfl(s, 0, 64); ss = __shfl(ss, 0, 64);
        float mu = s * (1.f / 128.f);
        float var = ss * (1.f / 128.f) - mu * mu;
        float rs = rsqrtf(var + 1e-5f);
        sy[r][ln_]      = (v0 - mu) * rs * g[ln_]      + be[ln_];
        sy[r][64 + ln_] = (v1 - mu) * rs * g[64 + ln_] + be[64 + ln_];
    }
    __syncthreads();
    #pragma unroll
    for (int th = 0; th < 2; th++){
        int t = tid + th * 256;
        float acc[16];
        #pragma unroll
        for (int r = 0; r < 16; r++) acc[r] = cb1[t];
        for (int k = 0; k < D_; k++){
            float w = cW1[k * CH_ + t];
            #pragma unroll
            for (int r = 0; r < 16; r++) acc[r] = fmaf(sy[r][k], w, acc[r]);
        }
        #pragma unroll
        for (int r = 0; r < 16; r++) sh[r][t] = gelu_t(acc[r]);
    }
    __syncthreads();
    {
        int d = tid & 127, rbase = tid >> 7;
        float acc[8];
        #pragma unroll
        for (int q = 0; q < 8; q++) acc[q] = 0.f;
        for (int t = 0; t < CH_; t++){
            float w = cW2[t * D_ + d];
            #pragma unroll
            for (int q = 0; q < 8; q++) acc[q] = fmaf(sh[rbase + 2 * q][t], w, acc[q]);
        }
        float cb = cb2[d];
        #pragma unroll
        for (int q = 0; q < 8; q++){
            int row = r0 + rbase + 2 * q;
            m[(long)row * D_ + d] += acc[q] + cb;
        }
    }
}

// ---------------- final pooled head ----------------
__global__ __launch_bounds__(128)
void k_final(const float* __restrict__ m, const float* __restrict__ oW1, const float* __restrict__ ob1,
             const float* __restrict__ oW2, const float* __restrict__ ob2, float* __restrict__ out){
    __shared__ float sp[D_];
    __shared__ float red[128];
    int b = blockIdx.x, tid = threadIdx.x;
    float a = 0.f;
    for (int p = 0; p < P_; p++) a += m[(long)b * P_ * D_ + p * D_ + tid];
    sp[tid] = a * (1.0f / P_);
    __syncthreads();
    float h = ob1[tid];
    for (int d = 0; d < D_; d++) h = fmaf(sp[d], oW1[d * D_ + tid], h);
    h = fmaxf(h, 0.f) * oW2[tid];
    red[tid] = h;
    __syncthreads();
    for (int s = 64; s > 0; s >>= 1){
        if (tid < s) red[tid] += red[tid + s];
        __syncthreads();
    }
    if (tid == 0) out[b] = red[0] + ob2[0];
}

extern "C" void kernel_launch(void* const* d_in, const int* in_sizes, int n_in,
                              void* d_out, int out_size, void* d_ws, size_t ws_size,
                              hipStream_t stream){
    const int*   x_atom       = (const int*)  d_in[0];
    const float* rw_pe        = (const float*)d_in[1];
    const int*   edge_attr    = (const int*)  d_in[2];
    const int*   nodes_mapper = (const int*)  d_in[3];
    const int*   edges_mapper = (const int*)  d_in[4];
    const int*   edge_index   = (const int*)  d_in[5];
    const int*   batch_x      = (const int*)  d_in[6];
    const float* patch_pe     = (const float*)d_in[7];
    // d_in[8] = mask, all-true by construction -> mean pooling
    const float* atom_emb = (const float*)d_in[9];
    const float* bond_emb = (const float*)d_in[10];
    const float* rw_W  = (const float*)d_in[11];
    const float* rw_b  = (const float*)d_in[12];
    const float* prw_W = (const float*)d_in[13];
    const float* prw_b = (const float*)d_in[14];
    const float* gnn_W = (const float*)d_in[15];
    const float* gnn_b = (const float*)d_in[16];
    const float* U_W   = (const float*)d_in[17];
    const float* U_b   = (const float*)d_in[18];
    const float* ln1_g = (const float*)d_in[19];
    const float* ln1_b = (const float*)d_in[20];
    const float* tW1   = (const float*)d_in[21];
    const float* tb1   = (const float*)d_in[22];
    const float* tW2   = (const float*)d_in[23];
    const float* tb2   = (const float*)d_in[24];
    const float* ln2_g = (const float*)d_in[25];
    const float* ln2_b = (const float*)d_in[26];
    const float* cW1   = (const float*)d_in[27];
    const float* cb1   = (const float*)d_in[28];
    const float* cW2   = (const float*)d_in[29];
    const float* cb2   = (const float*)d_in[30];
    const float* oW1   = (const float*)d_in[31];
    const float* ob1   = (const float*)d_in[32];
    const float* oW2   = (const float*)d_in[33];
    const float* ob2   = (const float*)d_in[34];

    const int* srcv = edge_index;
    const int* dstv = edge_index + ES_;

    // ---- workspace layout: ~202 MB <= 256 MiB ----
    char* w = (char*)d_ws;
    size_t offXS  = 0;                                        // per-copy state [NS,128] bf16 (NODE-major)
    size_t offXN  = offXS  + (size_t)NS_ * D_ * 2;            // compact [N,128] bf16
    size_t offRP  = offXN  + (size_t)N_ORIG * D_ * 2;
    size_t offEP  = offRP  + 2000064;
    size_t offDST2= offEP  + (size_t)ES_ * 4;
    size_t offPRP = offDST2+ (size_t)ES_ * 4;
    size_t offNRP = offPRP + 32832;
    size_t offPL  = offNRP + 800064;
    size_t offPERM= offPL  + (size_t)NS_ * 4;
    size_t offBX2 = offPERM+ (size_t)NS_ * 4;
    size_t offNM2 = offBX2 + (size_t)NS_ * 4;
    size_t offBS  = offNM2 + (size_t)NS_ * 4;
    size_t offST  = offBS  + 2048;
    size_t offM   = offST  + (size_t)BP_ * D_ * 2;
    size_t needed = offM   + (size_t)BP_ * D_ * 4;

    if (ws_size < needed){
        k_breadcrumb<<<cdiv_l(out_size, 256), 256, 0, stream>>>((float*)d_out, out_size,
                                                                (float)(ws_size >> 20));
        return;
    }

    // canary: absmax ~6.7 -> pipeline died mid-way; ~0.32 -> module never ran
    k_breadcrumb<<<cdiv_l(out_size, 256), 256, 0, stream>>>((float*)d_out, out_size, 7.0f);

    ushort_t* xs = (ushort_t*)(w + offXS);
    ushort_t* xn = (ushort_t*)(w + offXN);
    int* rp    = (int*)(w + offRP);
    int* ep    = (int*)(w + offEP);
    int* dst2  = (int*)(w + offDST2);
    int* prp   = (int*)(w + offPRP);
    int* nrp   = (int*)(w + offNRP);
    int* plist = (int*)(w + offPL);
    int* perm  = (int*)(w + offPERM);
    int* bx2   = (int*)(w + offBX2);
    int* nm2   = (int*)(w + offNM2);
    int* bsum  = (int*)(w + offBS);
    ushort_t* subT = (ushort_t*)(w + offST);
    float*    mbuf = (float*)(w + offM);
    // cursors borrow xs (dead until conv 0 writes it)
    int* cur_e = (int*)(w + offXS);
    int* cur_p = (int*)(w + offXS + 4194304);
    int* cur_n = (int*)(w + offXS + 8388608);

    const int TPB = 256;

    // ---- patch & node degree histograms, scans ----
    hipMemsetAsync(prp, 0, 32832, stream);
    hipMemsetAsync(nrp, 0, 800064, stream);
    k_deg_ns<<<cdiv_l(NS_, TPB), TPB, 0, stream>>>(batch_x, nodes_mapper, prp, nrp);
    k_scan1<<<cdiv_l(BP_, 1024), TPB, 0, stream>>>(prp, bsum, BP_);
    k_scan2<<<1, 512, 0, stream>>>(bsum, cdiv_l(BP_, 1024));
    k_scan3<<<cdiv_l(BP_ + 1, TPB), TPB, 0, stream>>>(prp, bsum, cur_p, BP_, NS_);
    k_scan1<<<cdiv_l(N_ORIG, 1024), TPB, 0, stream>>>(nrp, bsum, N_ORIG);
    k_scan2<<<1, 512, 0, stream>>>(bsum, cdiv_l(N_ORIG, 1024));
    k_scan3<<<cdiv_l(N_ORIG + 1, TPB), TPB, 0, stream>>>(nrp, bsum, cur_n, N_ORIG, NS_);
    // ---- relabeling scatter (node-major) ----
    k_scatter_ns<<<cdiv_l(NS_, TPB), TPB, 0, stream>>>(batch_x, nodes_mapper, cur_p, cur_n,
                                                       perm, bx2, nm2, plist);
    // ---- edge CSR over node-major dst ----
    hipMemsetAsync(rp, 0, 2000064, stream);
    k_deg_edges<<<cdiv_l(ES_, TPB), TPB, 0, stream>>>(dstv, perm, rp, dst2);
    k_scan1<<<cdiv_l(NS_, 1024), TPB, 0, stream>>>(rp, bsum, NS_);
    k_scan2<<<1, 512, 0, stream>>>(bsum, cdiv_l(NS_, 1024));
    k_scan3<<<cdiv_l(NS_ + 1, TPB), TPB, 0, stream>>>(rp, bsum, cur_e, NS_, ES_);
    k_scatter_edges<<<cdiv_l(ES_, TPB), TPB, 0, stream>>>(srcv, dst2, edge_attr, edges_mapper,
                                                          nodes_mapper, cur_e, ep);

    // ---- encode (compact, N rows) ----
    k_encode<<<cdiv_l((long)N_ORIG * 32, TPB), TPB, 0, stream>>>(x_atom, rw_pe, atom_emb,
                                                                 rw_W, rw_b, xn);

    for (int i = 0; i < 4; i++){
        if (i > 0){
            k_pool_gemm<<<BP_ / 16, 512, 0, stream>>>(xs, prp, plist,
                                                      U_W + (i - 1) * D_ * D_,
                                                      U_b + (i - 1) * D_, subT);
            k_node_resync<<<N_ORIG, 128, 0, stream>>>(xs, subT, bx2, nrp, xn);
        }
        k_conv_mfma<<<4096, 512, 0, stream>>>(xn, nm2, xs, rp, ep, bond_emb,
                                              gnn_W + i * D_ * D_, gnn_b + i * D_);
    }

    // ---- patch pooling + mixer ----
    k_patch_pool_sx<<<BP_, 256, 0, stream>>>(xs, prp, plist, patch_pe, prw_W, prw_b, mbuf);

    for (int l = 0; l < 2; l++){
        k_token_mix<<<B_, TPB, 0, stream>>>(mbuf, ln1_g + l * D_, ln1_b + l * D_,
                                            tW1 + l * P_ * TH_, tb1 + l * TH_,
                                            tW2 + l * TH_ * P_, tb2 + l * P_);
        k_channel_mix<<<BP_ / 16, TPB, 0, stream>>>(mbuf, ln2_g + l * D_, ln2_b + l * D_,
                                                    cW1 + l * D_ * CH_, cb1 + l * CH_,
                                                    cW2 + l * CH_ * D_, cb2 + l * D_);
    }
    k_final<<<B_, 128, 0, stream>>>(mbuf, oW1, ob1, oW2, ob2, (float*)d_out);
}